// Round 3
// baseline (528.454 us; speedup 1.0000x reference)
//
#include <hip/hip_runtime.h>

typedef unsigned short u16;

__device__ __forceinline__ float bf2f(u16 u) {
    unsigned int x = ((unsigned int)u) << 16;
    return __builtin_bit_cast(float, x);
}
__device__ __forceinline__ u16 f2bf(float f) {
    __bf16 h = (__bf16)f;
    return __builtin_bit_cast(u16, h);
}
// dtype-flag-aware input load: flag==1 -> buffer is f32, else bf16(u16)
__device__ __forceinline__ float ldin(const void* p, size_t i, int is_f32) {
    return is_f32 ? ((const float*)p)[i] : bf2f(((const u16*)p)[i]);
}

// ---------------- workspace layout (float offsets) ----------------
constexpr size_t FRW1 = 0;          // 1728
constexpr size_t FRB1 = 1728;       // 64
constexpr size_t FRW2 = 1792;       // 36864
constexpr size_t FRB2 = 38656;      // 64
constexpr size_t FRW3 = 38720;      // 36864
constexpr size_t FRB3 = 75584;      // 64
constexpr size_t VRW1 = 75648;      // 1728
constexpr size_t VRB1 = 77376;      // 64
constexpr size_t VRW2 = 77440;      // 36864
constexpr size_t VRB2 = 114304;     // 64
constexpr size_t VRW3 = 114368;     // 576
constexpr size_t VRB3 = 114944;     // 1
constexpr size_t MLPW1 = 114952;    // 4288
constexpr size_t MLPB1 = 119240;    // 64
constexpr size_t MLPW2 = 119304;    // 4096
constexpr size_t MLPB2 = 123400;    // 64
constexpr size_t MLPW3 = 123464;    // 64
constexpr size_t MLPB3 = 123528;    // 1
constexpr size_t CONFW = 123532;    // 64
constexpr size_t CONFB = 123596;    // 1
constexpr size_t FLAG  = 123600;    // 16 (1 int used)
constexpr size_t PACKA = 123616;    // 24192
constexpr size_t PACKB = 147808;    // 43008
constexpr size_t BUFA  = 190816;    // 917504 (refinement needs 14*64*1024)
constexpr size_t BUFB  = 1108320;   // 917504
constexpr size_t FEATF = 2025824;   // 516096 (f32 now)
constexpr size_t NVOFF = 2541920;   // 28672
constexpr size_t CFOFF = 2570592;   // 28672
constexpr size_t NOVEL = 2599264;   // 14336
// total 2613600 floats = ~10.45 MB

// ---------------- dtype detection ----------------
// Probe lf_sparse (~N(0,1), 8064 elems). Examine even-index u16s of the first
// 4096 bytes: if the buffer is bf16, these are real bf16 values -> exponent
// field in [100,130] nearly always. If f32, these are mantissa low-halves ->
// ~12% hit rate. Threshold at 60%.
__global__ void flag_kernel(const void* probe, int* flag) {
    __shared__ int cnt[256];
    int t = threadIdx.x;
    const u16* p = (const u16*)probe;
    int c = 0;
    for (int i = t; i < 1024; i += 256) {
        u16 u = p[2 * i];
        int e = (u >> 7) & 0xFF;
        c += (e >= 100 && e <= 130) ? 1 : 0;
    }
    cnt[t] = c;
    __syncthreads();
    for (int s2 = 128; s2 > 0; s2 >>= 1) {
        if (t < s2) cnt[t] += cnt[t + s2];
        __syncthreads();
    }
    if (t == 0) *flag = (cnt[0] < 614) ? 1 : 0; // 1 = f32, 0 = bf16
}

// ---------------- prep: input weights -> f32 in ws ----------------
struct Seg { const void* src; int off; int n; };
struct PrepArgs { Seg seg[20]; };

__global__ void prep_kernel(PrepArgs a, float* __restrict__ ws, const int* __restrict__ flag) {
    const int is_f32 = *flag;
    int tid = blockIdx.x * 256 + threadIdx.x;
    int stride = gridDim.x * 256;
    for (int sIdx = 0; sIdx < 20; ++sIdx) {
        const void* src = a.seg[sIdx].src;
        float* dst = ws + a.seg[sIdx].off;
        int n = a.seg[sIdx].n;
        for (int i = tid; i < n; i += stride) dst[i] = ldin(src, i, is_f32);
    }
}

// ---------------- pack kernels ----------------
__global__ void packA_kernel(const void* __restrict__ flow, const void* __restrict__ lf,
                             const void* __restrict__ wp, float* __restrict__ out,
                             const int* __restrict__ flag) {
    const int is_f32 = *flag;
    int tid = blockIdx.x * 256 + threadIdx.x;
    if (tid >= 4 * 2016) return;
    int m = tid / 2016, p = tid % 2016;
    size_t base = (size_t)m * 3 * 2016;
    out[base + p]          = ldin(flow, tid, is_f32);  // concat order: [fl, lf, wp]
    out[base + 2016 + p]   = ldin(lf, tid, is_f32);
    out[base + 4032 + p]   = ldin(wp, tid, is_f32);
}

__global__ void packB_kernel(const float* __restrict__ novel, const void* __restrict__ pl,
                             const void* __restrict__ pr, float* __restrict__ out,
                             const int* __restrict__ flag) {
    const int is_f32 = *flag;
    int tid = blockIdx.x * 256 + threadIdx.x;
    if (tid >= 14 * 1024) return;
    int m = tid >> 10, p = tid & 1023;
    size_t base = (size_t)m * 3072;
    out[base + p]        = novel[tid];         // concat order: [pn, pl, pr]
    out[base + 1024 + p] = ldin(pl, tid, is_f32);
    out[base + 2048 + p] = ldin(pr, tid, is_f32);
}

// ---------------- generic 3x3 SAME conv, f32 ----------------
// OUTMODE: 0 = f32 to outf; 2 = final output, dtype chosen by runtime flag.
template<int CIN, int OG, bool RELU, bool RESID, int OUTMODE>
__global__ __launch_bounds__(256) void conv3x3_kernel(
    const float* __restrict__ in, const float* __restrict__ wts,
    const float* __restrict__ bias, float* __restrict__ outf,
    void* __restrict__ outv, const float* __restrict__ resid, int rstride,
    const int* __restrict__ flag, int H, int W, int Cout)
{
    const int HW = H * W;
    const int t = threadIdx.x;
    const int cg = blockIdx.x, pt = blockIdx.y, m = blockIdx.z;
    const int c0 = cg * OG;
    __shared__ __align__(16) float lds_w[CIN * 9 * OG];
    for (int i = t; i < CIN * 9 * OG; i += 256) {
        int og = i % OG, tap = (i / OG) % 9, cin = i / (OG * 9);
        lds_w[(cin * 9 + tap) * OG + og] = wts[((size_t)(c0 + og) * CIN + cin) * 9 + tap];
    }
    __syncthreads();
    int p0 = pt * 512 + t;
    int p1 = p0 + 256;
    int y0 = p0 / W, x0 = p0 - y0 * W;
    int y1 = p1 / W, x1 = p1 - y1 * W;
    float acc0[OG], acc1[OG];
#pragma unroll
    for (int og = 0; og < OG; ++og) { acc0[og] = bias[c0 + og]; acc1[og] = acc0[og]; }
    const float* inm = in + (size_t)m * CIN * HW;
    for (int cin = 0; cin < CIN; ++cin) {
        const float* ip = inm + (size_t)cin * HW;
#pragma unroll
        for (int dy = 0; dy < 3; ++dy) {
            int yy0 = y0 + dy - 1, yy1 = y1 + dy - 1;
            bool r0 = (yy0 >= 0) && (yy0 < H);
            bool r1 = (yy1 >= 0) && (yy1 < H);
#pragma unroll
            for (int dx = 0; dx < 3; ++dx) {
                int xx0 = x0 + dx - 1, xx1 = x1 + dx - 1;
                float f0 = (r0 && xx0 >= 0 && xx0 < W) ? ip[yy0 * W + xx0] : 0.f;
                float f1 = (r1 && xx1 >= 0 && xx1 < W) ? ip[yy1 * W + xx1] : 0.f;
                const float* wv = &lds_w[(cin * 9 + dy * 3 + dx) * OG];
#pragma unroll
                for (int og = 0; og < OG; ++og) {
                    acc0[og] += f0 * wv[og];
                    acc1[og] += f1 * wv[og];
                }
            }
        }
    }
    int is_f32 = 0;
    if constexpr (OUTMODE == 2) is_f32 = *flag;
#pragma unroll
    for (int og = 0; og < OG; ++og) {
        int c = c0 + og;
        float a0 = acc0[og], a1 = acc1[og];
        if constexpr (RELU) { a0 = fmaxf(a0, 0.f); a1 = fmaxf(a1, 0.f); }
        if (p0 < HW) {
            float vv = a0;
            if constexpr (RESID) vv += resid[(size_t)m * rstride + p0];
            size_t idx = ((size_t)m * Cout + c) * HW + p0;
            if constexpr (OUTMODE == 0) outf[idx] = vv;
            else { if (is_f32) ((float*)outv)[idx] = vv; else ((u16*)outv)[idx] = f2bf(vv); }
        }
        if (p1 < HW) {
            float vv = a1;
            if constexpr (RESID) vv += resid[(size_t)m * rstride + p1];
            size_t idx = ((size_t)m * Cout + c) * HW + p1;
            if constexpr (OUTMODE == 0) outf[idx] = vv;
            else { if (is_f32) ((float*)outv)[idx] = vv; else ((u16*)outv)[idx] = f2bf(vv); }
        }
    }
}

// ---------------- VALU MLP: one thread per (bs, n, k) ----------------
__global__ __launch_bounds__(256) void mlp_valu_kernel(
    const void* __restrict__ lf, const void* __restrict__ flow,
    const float* __restrict__ feat, const float* __restrict__ wsf,
    float* __restrict__ nv_out, float* __restrict__ cf_out,
    const int* __restrict__ flag)
{
    const int is_f32 = *flag;
    const int t = threadIdx.x;
    const int blk = blockIdx.x;
    const int bs = blk >> 7;
    const int n0 = (blk & 127) * 8;
    const int b = bs >> 1, s = bs & 1;
    const int nl = t >> 5, k = t & 31;
    const int n = n0 + nl;
    const int hh_ = n >> 5, jj_ = n & 31;
    const int apos = (bs * 32 + hh_) * 63 + jj_ + k;
    const float flowv = ldin(flow, apos, is_f32);
    const float epiv  = ldin(lf, apos, is_f32);
    const float spat  = (float)(k - 16);

    const float* w1f = wsf + MLPW1;
    const float* b1f = wsf + MLPB1;
    const float* w2f = wsf + MLPW2;
    const float* b2f = wsf + MLPB2;
    const float* w3f = wsf + MLPW3;
    const float* cwf = wsf + CONFW;
    const float  b3s = wsf[MLPB3];
    const float  cbs = wsf[CONFB];

    float base[64];
#pragma unroll
    for (int j1 = 0; j1 < 64; ++j1)
        base[j1] = b1f[j1] + flowv * w1f[j1] + spat * w1f[65 * 64 + j1];

    const int fpos = hh_ * 63 + jj_ + k;
    const float* fp = feat + (size_t)bs * 64 * 2016 + fpos;
#pragma unroll 1
    for (int c = 0; c < 64; ++c) {
        float xc = fp[(size_t)c * 2016];
        const float* wr = w1f + (1 + c) * 64;
#pragma unroll
        for (int j1 = 0; j1 < 64; ++j1) base[j1] += xc * wr[j1];
    }

#pragma unroll 1
    for (int v = 0; v < 7; ++v) {
        const float ang = (s == 0) ? -(float)(v + 1) : (float)(7 - v);
        float wls = 0.f, cfs = 0.f;
#pragma unroll 1
        for (int hf = 0; hf < 2; ++hf) {
            float acc2[32];
#pragma unroll
            for (int j2 = 0; j2 < 32; ++j2) acc2[j2] = b2f[hf * 32 + j2];
#pragma unroll
            for (int j1 = 0; j1 < 64; ++j1) {
                float hv = fmaxf(base[j1] + ang * w1f[66 * 64 + j1], 0.f);
                const float* w2r = w2f + j1 * 64 + hf * 32;
#pragma unroll
                for (int j2 = 0; j2 < 32; ++j2) acc2[j2] += hv * w2r[j2];
            }
#pragma unroll
            for (int j2 = 0; j2 < 32; ++j2) {
                float h2 = fmaxf(acc2[j2], 0.f);
                wls += h2 * w3f[hf * 32 + j2];
                cfs += h2 * cwf[hf * 32 + j2];
            }
        }
        float wl = wls + b3s;
        float mx = wl;
#pragma unroll
        for (int m2 = 1; m2 <= 16; m2 <<= 1) mx = fmaxf(mx, __shfl_xor(mx, m2));
        float e = __expf(wl - mx);
        float ssum = e, nvp = e * epiv, cfp = cfs;
#pragma unroll
        for (int m2 = 1; m2 <= 16; m2 <<= 1) {
            ssum += __shfl_xor(ssum, m2);
            nvp  += __shfl_xor(nvp, m2);
            cfp  += __shfl_xor(cfp, m2);
        }
        if (k == 0) {
            size_t idx = ((size_t)(b * 7 + v) * 2 + s) * 1024 + n;
            nv_out[idx] = nvp / ssum;
            cf_out[idx] = cfp * (1.f / 32.f) + cbs;
        }
    }
}

// ---------------- conf softmax over s + novel ----------------
__global__ void combine_kernel(const float* __restrict__ nv, const float* __restrict__ cf,
                               float* __restrict__ novel) {
    int tid = blockIdx.x * 256 + threadIdx.x;
    if (tid >= 2 * 7 * 1024) return;
    int n = tid & 1023;
    int bv = tid >> 10;
    size_t i0 = ((size_t)bv * 2 + 0) * 1024 + n;
    size_t i1 = ((size_t)bv * 2 + 1) * 1024 + n;
    float c0 = cf[i0], c1 = cf[i1];
    float mx = fmaxf(c0, c1);
    float e0 = __expf(c0 - mx), e1 = __expf(c1 - mx);
    novel[tid] = (e0 * nv[i0] + e1 * nv[i1]) / (e0 + e1);
}

// ---------------- launch ----------------
extern "C" void kernel_launch(void* const* d_in, const int* in_sizes, int n_in,
                              void* d_out, int out_size, void* d_ws, size_t ws_size,
                              hipStream_t stream) {
    const void* lf   = d_in[0];
    const void* flow = d_in[1];
    const void* wp   = d_in[2];
    const void* pl   = d_in[3];
    const void* pr   = d_in[4];
    float* ws = (float*)d_ws;
    int* flagp = (int*)(ws + FLAG);

    flag_kernel<<<1, 256, 0, stream>>>(lf, flagp);

    PrepArgs pa;
    const int srcIdx[20] = {5, 6, 7, 8, 9, 10, 19, 20, 21, 22, 23, 24,
                            11, 12, 13, 14, 15, 16, 17, 18};
    const int dstOff[20] = {(int)FRW1, (int)FRB1, (int)FRW2, (int)FRB2, (int)FRW3, (int)FRB3,
                            (int)VRW1, (int)VRB1, (int)VRW2, (int)VRB2, (int)VRW3, (int)VRB3,
                            (int)MLPW1, (int)MLPB1, (int)MLPW2, (int)MLPB2, (int)MLPW3,
                            (int)MLPB3, (int)CONFW, (int)CONFB};
    const int segN[20]   = {1728, 64, 36864, 64, 36864, 64, 1728, 64, 36864, 64, 576, 1,
                            4288, 64, 4096, 64, 64, 1, 64, 1};
    for (int i = 0; i < 20; ++i) {
        pa.seg[i].src = d_in[srcIdx[i]];
        pa.seg[i].off = dstOff[i];
        pa.seg[i].n   = segN[i];
    }
    prep_kernel<<<64, 256, 0, stream>>>(pa, ws, flagp);

    packA_kernel<<<32, 256, 0, stream>>>(flow, lf, wp, ws + PACKA, flagp);

    // feature net: (4,*,32,63)
    conv3x3_kernel<3, 4, true, false, 0><<<dim3(16, 4, 4), 256, 0, stream>>>(
        ws + PACKA, ws + FRW1, ws + FRB1, ws + BUFA, nullptr, nullptr, 0, flagp, 32, 63, 64);
    conv3x3_kernel<64, 4, true, false, 0><<<dim3(16, 4, 4), 256, 0, stream>>>(
        ws + BUFA, ws + FRW2, ws + FRB2, ws + BUFB, nullptr, nullptr, 0, flagp, 32, 63, 64);
    conv3x3_kernel<64, 4, true, false, 0><<<dim3(16, 4, 4), 256, 0, stream>>>(
        ws + BUFB, ws + FRW3, ws + FRB3, ws + FEATF, nullptr, nullptr, 0, flagp, 32, 63, 64);

    mlp_valu_kernel<<<512, 256, 0, stream>>>(
        lf, flow, ws + FEATF, ws, ws + NVOFF, ws + CFOFF, flagp);

    combine_kernel<<<56, 256, 0, stream>>>(ws + NVOFF, ws + CFOFF, ws + NOVEL);
    packB_kernel<<<56, 256, 0, stream>>>(ws + NOVEL, pl, pr, ws + PACKB, flagp);

    // refinement net: (14,*,32,32)
    conv3x3_kernel<3, 4, true, false, 0><<<dim3(16, 2, 14), 256, 0, stream>>>(
        ws + PACKB, ws + VRW1, ws + VRB1, ws + BUFA, nullptr, nullptr, 0, flagp, 32, 32, 64);
    conv3x3_kernel<64, 4, true, false, 0><<<dim3(16, 2, 14), 256, 0, stream>>>(
        ws + BUFA, ws + VRW2, ws + VRB2, ws + BUFB, nullptr, nullptr, 0, flagp, 32, 32, 64);
    conv3x3_kernel<64, 1, false, true, 2><<<dim3(1, 2, 14), 256, 0, stream>>>(
        ws + BUFB, ws + VRW3, ws + VRB3, nullptr, d_out, ws + PACKB, 3072, flagp, 32, 32, 1);
}

// Round 4
// 267.515 us; speedup vs baseline: 1.9754x; 1.9754x over previous
//
#include <hip/hip_runtime.h>

typedef unsigned short u16;
typedef __bf16 bf16x8 __attribute__((ext_vector_type(8)));
typedef float f32x4 __attribute__((ext_vector_type(4)));
typedef u16 u16x8 __attribute__((ext_vector_type(8)));

__device__ __forceinline__ u16 f2bf(float f) {
    __bf16 h = (__bf16)f;
    return __builtin_bit_cast(u16, h);
}
__device__ __forceinline__ float bf2f(u16 u) {
    unsigned int x = ((unsigned int)u) << 16;
    return __builtin_bit_cast(float, x);
}

union FragU { u16x8 u; bf16x8 v; };

// ---------------- workspace layout (float offsets) ----------------
constexpr size_t FEAT_A = 0;        // 917504 (max of 4*64*2016, 14*64*1024)
constexpr size_t FEAT_B = 917504;   // 917504
constexpr size_t FEATBF = 1835008;  // 258048 floats = 516096 u16 (bf16 feat)
constexpr size_t NVOFF  = 2093056;  // 28672
constexpr size_t CFOFF  = 2121728;  // 28672
constexpr size_t NOVEL  = 2150400;  // 14336
// total 2164736 floats = 8.66 MB

// ---------------- generic 3x3 SAME conv, f32, scalar-load weights ----------
// 1 pixel/thread, OG output channels/thread. Weights/bias indexed uniformly
// -> compiler emits s_load; FMAs take the weight as an SGPR operand (no LDS).
// OUTMODE: 0 = f32 to outf; 1 = bf16 to outb; 2 = f32 + resid (final out).
// TRIPLE: CIN==3 with three separate single-channel input pointers.
template<int CIN, int OG, bool RELU, int OUTMODE, bool TRIPLE>
__global__ __launch_bounds__(256) void conv3x3_kernel(
    const float* __restrict__ in0, const float* __restrict__ in1,
    const float* __restrict__ in2,
    const float* __restrict__ wts, const float* __restrict__ bias,
    float* __restrict__ outf, u16* __restrict__ outb,
    const float* __restrict__ resid,
    int H, int W, int Cout)
{
    const int HW = H * W;
    const int t = threadIdx.x;
    const int p = blockIdx.y * 256 + t;
    const int m = blockIdx.z;
    const int c0 = blockIdx.x * OG;
    if (p >= HW) return;
    const int y = p / W, x = p - y * W;

    float acc[OG];
#pragma unroll
    for (int og = 0; og < OG; ++og) acc[og] = bias[c0 + og];

#pragma unroll 2
    for (int cin = 0; cin < CIN; ++cin) {
        const float* ip;
        if constexpr (TRIPLE) {
            ip = (cin == 0 ? in0 : (cin == 1 ? in1 : in2)) + (size_t)m * HW;
        } else {
            ip = in0 + ((size_t)m * CIN + cin) * HW;
        }
        float tap[9];
#pragma unroll
        for (int dy = 0; dy < 3; ++dy) {
            int yy = y + dy - 1;
            bool ry = (yy >= 0) && (yy < H);
#pragma unroll
            for (int dx = 0; dx < 3; ++dx) {
                int xx = x + dx - 1;
                bool ok = ry && (xx >= 0) && (xx < W);
                tap[dy * 3 + dx] = ok ? ip[yy * W + xx] : 0.f;
            }
        }
#pragma unroll
        for (int og = 0; og < OG; ++og) {
            const float* wr = wts + ((size_t)(c0 + og) * CIN + cin) * 9;
#pragma unroll
            for (int j = 0; j < 9; ++j) acc[og] = fmaf(tap[j], wr[j], acc[og]);
        }
    }

#pragma unroll
    for (int og = 0; og < OG; ++og) {
        int c = c0 + og;
        float vv = acc[og];
        if constexpr (RELU) vv = fmaxf(vv, 0.f);
        size_t idx = ((size_t)m * Cout + c) * HW + p;
        if constexpr (OUTMODE == 0) outf[idx] = vv;
        else if constexpr (OUTMODE == 1) outb[idx] = f2bf(vv);
        else { vv += resid[(size_t)m * HW + p]; outf[idx] = vv; }
    }
}

// ---------------- fused MFMA MLP + softmax + epi-weighting ----------------
// grid 512 blocks (4 bs * 128 n-groups), block 256 thr = 4 waves.
// Rows r = nl*32 + k (8 n values x 32 disparity taps); wave w owns rows
// w*64..w*64+63. L1 (normal orient, 16x16x32 bf16 MFMA): base = X@W1[1:65]
// + rank-1 flow/spat/b1 terms, stored bf16 in LDS (row stride 72 u16 so the
// b128 transpose reads hit the 8-phase structural LDS minimum, not 16-way).
// L2 (transposed: A=W2^T regs, B=h1^T from LDS) puts the hidden dim in-lane;
// L3 weight/conf dots reduce with 2 shfl_xor. Softmax over k in-wave.
__global__ __launch_bounds__(256, 2) void mlp_mfma_kernel(
    const float* __restrict__ lf, const float* __restrict__ flow,
    const u16* __restrict__ feat,
    const float* __restrict__ w1, const float* __restrict__ b1,
    const float* __restrict__ w2, const float* __restrict__ b2,
    const float* __restrict__ w3, const float* __restrict__ b3g,
    const float* __restrict__ cw, const float* __restrict__ cbg,
    float* __restrict__ nv_out, float* __restrict__ cf_out)
{
    constexpr int SBS = 72; // s_base row stride (u16); 144B, 16B-aligned
    __shared__ u16 s_w1[67 * 64];
    __shared__ u16 s_w2[64 * 64];
    __shared__ __align__(16) float s_vec[7 * 64]; // b1,b2,w3,cw,w1r0,w1r65,w1r66
    __shared__ __align__(16) float s_flow[256];
    __shared__ __align__(16) float s_epi[256];
    __shared__ __align__(16) u16 s_base[256 * SBS];

    const int t = threadIdx.x;
    const int blk = blockIdx.x;
    const int bs = blk >> 7;
    const int n0 = (blk & 127) * 8;
    const int b = bs >> 1, s = bs & 1;
    const int w = t >> 6, lane = t & 63, q = lane >> 4, l15 = lane & 15;

    for (int i = t; i < 67 * 64; i += 256) s_w1[i] = f2bf(w1[i]);
    for (int i = t; i < 64 * 64; i += 256) s_w2[i] = f2bf(w2[i]);
    if (t < 64) {
        s_vec[t]       = b1[t];
        s_vec[64 + t]  = b2[t];
        s_vec[128 + t] = w3[t];
        s_vec[192 + t] = cw[t];
        s_vec[256 + t] = w1[t];            // row 0: flow weight
        s_vec[320 + t] = w1[65 * 64 + t];  // row 65: spatial
        s_vec[384 + t] = w1[66 * 64 + t];  // row 66: ang
    }
    {
        int nl = t >> 5, k = t & 31;
        int n = n0 + nl;
        int a = (bs * 32 + (n >> 5)) * 63 + (n & 31) + k;
        s_flow[t] = flow[a];
        s_epi[t]  = lf[a];
    }
    __syncthreads();

    const float b3s = b3g[0];
    const float cbs = cbg[0];

    // ---- layer 1: D1[r][j1], A = feat rows, B = W1 rows 1..64 ----
    FragU w1b[2][4];
#pragma unroll
    for (int ks = 0; ks < 2; ++ks)
#pragma unroll
        for (int nt = 0; nt < 4; ++nt)
#pragma unroll
            for (int jj = 0; jj < 8; ++jj)
                w1b[ks][nt].u[jj] = s_w1[(1 + ks * 32 + q * 8 + jj) * 64 + nt * 16 + l15];

    float w1r0pl[4], w1r65pl[4], b1pl[4];
#pragma unroll
    for (int nt = 0; nt < 4; ++nt) {
        int j1 = nt * 16 + l15;
        w1r0pl[nt]  = s_vec[256 + j1];
        w1r65pl[nt] = s_vec[320 + j1];
        b1pl[nt]    = s_vec[j1];
    }

#pragma unroll
    for (int mt = 0; mt < 4; ++mt) {
        const int rbase = w * 64 + mt * 16;
        FragU af[2];
        {
            int r = rbase + l15;
            int n = n0 + (r >> 5);
            int pos = (n >> 5) * 63 + (n & 31) + (r & 31);
            const u16* fp = feat + (size_t)bs * 64 * 2016 + pos;
#pragma unroll
            for (int ks = 0; ks < 2; ++ks)
#pragma unroll
                for (int jj = 0; jj < 8; ++jj)
                    af[ks].u[jj] = fp[(size_t)(ks * 32 + q * 8 + jj) * 2016];
        }
        f32x4 flow4 = *(const f32x4*)(s_flow + rbase + q * 4);
#pragma unroll
        for (int nt = 0; nt < 4; ++nt) {
            f32x4 d = {0.f, 0.f, 0.f, 0.f};
            d = __builtin_amdgcn_mfma_f32_16x16x32_bf16(af[0].v, w1b[0][nt].v, d, 0, 0, 0);
            d = __builtin_amdgcn_mfma_f32_16x16x32_bf16(af[1].v, w1b[1][nt].v, d, 0, 0, 0);
#pragma unroll
            for (int e = 0; e < 4; ++e) {
                int r = rbase + q * 4 + e;
                int k = r & 31;
                float val = d[e] + flow4[e] * w1r0pl[nt]
                          + (float)(k - 16) * w1r65pl[nt] + b1pl[nt];
                s_base[r * SBS + nt * 16 + l15] = f2bf(val);
            }
        }
    }
    __syncthreads();

    // ---- preloads for v-loop ----
    FragU w2a[4][2]; // A = W2^T : A[m=j2][k=j1] = w2[j1][j2]
#pragma unroll
    for (int mt = 0; mt < 4; ++mt)
#pragma unroll
        for (int ks = 0; ks < 2; ++ks)
#pragma unroll
            for (int jj = 0; jj < 8; ++jj)
                w2a[mt][ks].u[jj] = s_w2[(ks * 32 + q * 8 + jj) * 64 + mt * 16 + l15];

    float w66pl[2][8];
#pragma unroll
    for (int ks = 0; ks < 2; ++ks) {
        f32x4 lo = *(const f32x4*)(s_vec + 384 + ks * 32 + q * 8);
        f32x4 hi = *(const f32x4*)(s_vec + 384 + ks * 32 + q * 8 + 4);
#pragma unroll
        for (int jj = 0; jj < 4; ++jj) { w66pl[ks][jj] = lo[jj]; w66pl[ks][4 + jj] = hi[jj]; }
    }
    float b2pl[4][4], w3pl[4][4], cwpl[4][4];
#pragma unroll
    for (int mt = 0; mt < 4; ++mt) {
        f32x4 vb = *(const f32x4*)(s_vec + 64 + mt * 16 + q * 4);
        f32x4 vw = *(const f32x4*)(s_vec + 128 + mt * 16 + q * 4);
        f32x4 vc = *(const f32x4*)(s_vec + 192 + mt * 16 + q * 4);
#pragma unroll
        for (int e = 0; e < 4; ++e) { b2pl[mt][e] = vb[e]; w3pl[mt][e] = vw[e]; cwpl[mt][e] = vc[e]; }
    }
    float epi_pl[4];
#pragma unroll
    for (int nt = 0; nt < 4; ++nt) epi_pl[nt] = s_epi[w * 64 + nt * 16 + l15];

    // ---- per-view loop ----
    for (int v = 0; v < 7; ++v) {
        float ang = (s == 0) ? -(float)(v + 1) : (float)(7 - v);
        f32x4 acc[4][4];
#pragma unroll
        for (int nt = 0; nt < 4; ++nt) {
            FragU bfr[2]; // B = h1^T : B[k=j1][n=row]
#pragma unroll
            for (int ks = 0; ks < 2; ++ks) {
                const u16x8 raw = *(const u16x8*)(s_base + (w * 64 + nt * 16 + l15) * SBS + ks * 32 + q * 8);
#pragma unroll
                for (int jj = 0; jj < 8; ++jj) {
                    float xv = bf2f(raw[jj]);
                    float hv = fmaxf(xv + ang * w66pl[ks][jj], 0.f);
                    bfr[ks].u[jj] = f2bf(hv);
                }
            }
#pragma unroll
            for (int mt = 0; mt < 4; ++mt) {
                f32x4 d = {0.f, 0.f, 0.f, 0.f};
                d = __builtin_amdgcn_mfma_f32_16x16x32_bf16(w2a[mt][0].v, bfr[0].v, d, 0, 0, 0);
                d = __builtin_amdgcn_mfma_f32_16x16x32_bf16(w2a[mt][1].v, bfr[1].v, d, 0, 0, 0);
                acc[mt][nt] = d;
            }
        }
        // layer 3: hidden dim in-lane (j2 = mt*16 + q*4 + e); reduce across quads.
        float wl[4], cfl[4];
#pragma unroll
        for (int nt = 0; nt < 4; ++nt) {
            float wls = 0.f, cfs = 0.f;
#pragma unroll
            for (int mt = 0; mt < 4; ++mt)
#pragma unroll
                for (int e = 0; e < 4; ++e) {
                    float h2 = fmaxf(acc[mt][nt][e] + b2pl[mt][e], 0.f);
                    wls += h2 * w3pl[mt][e];
                    cfs += h2 * cwpl[mt][e];
                }
            wls += __shfl_xor(wls, 16); wls += __shfl_xor(wls, 32);
            cfs += __shfl_xor(cfs, 16); cfs += __shfl_xor(cfs, 32);
            wl[nt]  = wls + b3s;
            cfl[nt] = cfs;
        }
        // softmax over k(32): rows (nt, l15) pair into n = n0 + w*2 + ni.
#pragma unroll
        for (int ni = 0; ni < 2; ++ni) {
            float a0 = wl[ni * 2], a1 = wl[ni * 2 + 1];
            float mx = fmaxf(a0, a1);
#pragma unroll
            for (int msk = 1; msk <= 8; msk <<= 1) mx = fmaxf(mx, __shfl_xor(mx, msk));
            float e0 = __expf(a0 - mx), e1 = __expf(a1 - mx);
            float ssum = e0 + e1;
            float nvp = e0 * epi_pl[ni * 2] + e1 * epi_pl[ni * 2 + 1];
            float cfp = cfl[ni * 2] + cfl[ni * 2 + 1];
#pragma unroll
            for (int msk = 1; msk <= 8; msk <<= 1) {
                ssum += __shfl_xor(ssum, msk);
                nvp  += __shfl_xor(nvp, msk);
                cfp  += __shfl_xor(cfp, msk);
            }
            if (lane == 0) {
                int n = n0 + w * 2 + ni;
                size_t idx = ((size_t)(b * 7 + v) * 2 + s) * 1024 + n;
                nv_out[idx] = nvp / ssum;
                cf_out[idx] = cfp * (1.f / 32.f) + cbs;
            }
        }
    }
}

// ---------------- conf softmax over s + novel ----------------
__global__ void combine_kernel(const float* __restrict__ nv, const float* __restrict__ cf,
                               float* __restrict__ novel) {
    int tid = blockIdx.x * 256 + threadIdx.x;
    if (tid >= 2 * 7 * 1024) return;
    int n = tid & 1023;
    int bv = tid >> 10;
    size_t i0 = ((size_t)bv * 2 + 0) * 1024 + n;
    size_t i1 = ((size_t)bv * 2 + 1) * 1024 + n;
    float c0 = cf[i0], c1 = cf[i1];
    float mx = fmaxf(c0, c1);
    float e0 = __expf(c0 - mx), e1 = __expf(c1 - mx);
    novel[tid] = (e0 * nv[i0] + e1 * nv[i1]) / (e0 + e1);
}

// ---------------- launch ----------------
extern "C" void kernel_launch(void* const* d_in, const int* in_sizes, int n_in,
                              void* d_out, int out_size, void* d_ws, size_t ws_size,
                              hipStream_t stream) {
    const float* lf   = (const float*)d_in[0];
    const float* flow = (const float*)d_in[1];
    const float* wp   = (const float*)d_in[2];
    const float* pl   = (const float*)d_in[3];
    const float* pr   = (const float*)d_in[4];
    const float* frw1 = (const float*)d_in[5];
    const float* frb1 = (const float*)d_in[6];
    const float* frw2 = (const float*)d_in[7];
    const float* frb2 = (const float*)d_in[8];
    const float* frw3 = (const float*)d_in[9];
    const float* frb3 = (const float*)d_in[10];
    const float* mw1  = (const float*)d_in[11];
    const float* mb1  = (const float*)d_in[12];
    const float* mw2  = (const float*)d_in[13];
    const float* mb2  = (const float*)d_in[14];
    const float* mw3  = (const float*)d_in[15];
    const float* mb3  = (const float*)d_in[16];
    const float* cwp  = (const float*)d_in[17];
    const float* cbp  = (const float*)d_in[18];
    const float* vrw1 = (const float*)d_in[19];
    const float* vrb1 = (const float*)d_in[20];
    const float* vrw2 = (const float*)d_in[21];
    const float* vrb2 = (const float*)d_in[22];
    const float* vrw3 = (const float*)d_in[23];
    const float* vrb3 = (const float*)d_in[24];
    float* ws = (float*)d_ws;

    // feature net on (4,*,32,63); concat order [flow, lf, wp]
    conv3x3_kernel<3, 8, true, 0, true><<<dim3(8, 8, 4), 256, 0, stream>>>(
        flow, lf, wp, frw1, frb1, ws + FEAT_A, nullptr, nullptr, 32, 63, 64);
    conv3x3_kernel<64, 4, true, 0, false><<<dim3(16, 8, 4), 256, 0, stream>>>(
        ws + FEAT_A, nullptr, nullptr, frw2, frb2, ws + FEAT_B, nullptr, nullptr, 32, 63, 64);
    conv3x3_kernel<64, 4, true, 1, false><<<dim3(16, 8, 4), 256, 0, stream>>>(
        ws + FEAT_B, nullptr, nullptr, frw3, frb3, nullptr, (u16*)(ws + FEATBF), nullptr, 32, 63, 64);

    mlp_mfma_kernel<<<512, 256, 0, stream>>>(
        lf, flow, (const u16*)(ws + FEATBF),
        mw1, mb1, mw2, mb2, mw3, mb3, cwp, cbp,
        ws + NVOFF, ws + CFOFF);

    combine_kernel<<<56, 256, 0, stream>>>(ws + NVOFF, ws + CFOFF, ws + NOVEL);

    // refinement net on (14,*,32,32); concat order [pn, pl, pr]
    conv3x3_kernel<3, 8, true, 0, true><<<dim3(8, 4, 14), 256, 0, stream>>>(
        ws + NOVEL, pl, pr, vrw1, vrb1, ws + FEAT_A, nullptr, nullptr, 32, 32, 64);
    conv3x3_kernel<64, 4, true, 0, false><<<dim3(16, 4, 14), 256, 0, stream>>>(
        ws + FEAT_A, nullptr, nullptr, vrw2, vrb2, ws + FEAT_B, nullptr, nullptr, 32, 32, 64);
    conv3x3_kernel<64, 1, false, 2, false><<<dim3(1, 4, 14), 256, 0, stream>>>(
        ws + FEAT_B, nullptr, nullptr, vrw3, vrb3, (float*)d_out, nullptr, ws + NOVEL, 32, 32, 1);
}

// Round 5
// 241.300 us; speedup vs baseline: 2.1900x; 1.1086x over previous
//
#include <hip/hip_runtime.h>

typedef unsigned short u16;
typedef unsigned int u32;
typedef __bf16 bf16x8 __attribute__((ext_vector_type(8)));
typedef float f32x4 __attribute__((ext_vector_type(4)));
typedef u16 u16x8 __attribute__((ext_vector_type(8)));

__device__ __forceinline__ u16 f2bf(float f) {
    __bf16 h = (__bf16)f;
    return __builtin_bit_cast(u16, h);
}
__device__ __forceinline__ float bf2f(u16 u) {
    unsigned int x = ((unsigned int)u) << 16;
    return __builtin_bit_cast(float, x);
}

union FragU { u16x8 u; bf16x8 v; };

// unaligned (4B-aligned) float4 load
struct __attribute__((packed)) F4P { f32x4 v; };
__device__ __forceinline__ f32x4 ld4u(const float* p) { return ((const F4P*)p)->v; }

// ---------------- workspace layout (float offsets) ----------------
// 16-float guards around vector-loaded buffers (conv64 reads base-1 .. end+2).
constexpr size_t FEAT_A = 16;       // 917504 = max(4*64*2016, 14*64*1024)
constexpr size_t FEAT_B = 917536;   // 917504
constexpr size_t FEATBF = 1835056;  // 258048 floats = 516096 u16, layout [bs][2016][64]
constexpr size_t NOVEL  = 2093120;  // 14336  [b*7+v][1024]
// total ~2107472 floats = 8.43 MB

// ---------------- 3-channel 3x3 SAME conv (scalar taps, f32) ----------------
// in0/in1/in2: single-channel images [M][HW]. out: f32 NCHW.
template<int OG>
__global__ __launch_bounds__(256) void conv3_kernel(
    const float* __restrict__ in0, const float* __restrict__ in1,
    const float* __restrict__ in2,
    const float* __restrict__ wts, const float* __restrict__ bias,
    float* __restrict__ outf, int H, int W, int Cout)
{
    const int HW = H * W;
    const int t = threadIdx.x;
    const int p = blockIdx.y * 256 + t;
    const int m = blockIdx.z;
    const int c0 = blockIdx.x * OG;
    if (p >= HW) return;
    const int y = p / W, x = p - y * W;

    float acc[OG];
#pragma unroll
    for (int og = 0; og < OG; ++og) acc[og] = bias[c0 + og];

#pragma unroll
    for (int cin = 0; cin < 3; ++cin) {
        const float* ip = (cin == 0 ? in0 : (cin == 1 ? in1 : in2)) + (size_t)m * HW;
        float tap[9];
#pragma unroll
        for (int dy = 0; dy < 3; ++dy) {
            int yy = y + dy - 1;
            bool ry = (yy >= 0) && (yy < H);
#pragma unroll
            for (int dx = 0; dx < 3; ++dx) {
                int xx = x + dx - 1;
                bool ok = ry && (xx >= 0) && (xx < W);
                tap[dy * 3 + dx] = ok ? ip[yy * W + xx] : 0.f;
            }
        }
#pragma unroll
        for (int og = 0; og < OG; ++og) {
            const float* wr = wts + ((size_t)(c0 + og) * 3 + cin) * 9;
#pragma unroll
            for (int j = 0; j < 9; ++j) acc[og] = fmaf(tap[j], wr[j], acc[og]);
        }
    }
#pragma unroll
    for (int og = 0; og < OG; ++og) {
        float vv = fmaxf(acc[og], 0.f);
        outf[((size_t)m * Cout + c0 + og) * HW + p] = vv;
    }
}

// ---------------- 64-channel 3x3 SAME conv, vectorized rows ----------------
// 2 px (x0, x0+1) x OG=2 och per thread. Per cin: 3 x dwordx4 row loads
// (floats x0-1..x0+2, guarded buffers) + 36 FMA with scalar (SGPR) weights.
// OUTMODE 0: f32 NCHW (+relu). OUTMODE 1: bf16 [m][p][64] (+relu).
template<int OUTMODE>
__global__ __launch_bounds__(256) void conv64_kernel(
    const float* __restrict__ in,   // [M][64][HW] in guarded ws
    const float* __restrict__ wts,  // [Cout][64][9]
    const float* __restrict__ bias,
    float* __restrict__ outf, u16* __restrict__ outb,
    int H, int W, int W2, int Cout)
{
    const int HW = H * W;
    const int t = threadIdx.x;
    const int p2 = blockIdx.y * 256 + t;
    const int m = blockIdx.z;
    const int c0 = blockIdx.x * 2;
    const int y = p2 / W2;
    const int x0 = (p2 - y * W2) * 2;
    const bool xlo = (x0 == 0);
    const bool ze2 = (x0 + 1 > W - 1);   // element2 (x0+1) out of range
    const bool ze3 = (x0 + 2 > W - 1);   // element3 (x0+2) out of range
    const bool px1ok = (x0 + 1 < W);
    const bool y0ok = (y > 0);
    const bool y2ok = (y + 1 < H);

    float a00 = bias[c0],     a01 = a00;
    float a10 = bias[c0 + 1], a11 = a10;

    const float* ipm = in + (size_t)m * 64 * HW + y * W + (x0 - 1);
    const float* wb0 = wts + (size_t)c0 * 64 * 9;
    const float* wb1 = wts + (size_t)(c0 + 1) * 64 * 9;
    const f32x4 zz = {0.f, 0.f, 0.f, 0.f};

#pragma unroll 2
    for (int cin = 0; cin < 64; ++cin) {
        const float* ip = ipm + (size_t)cin * HW;
        f32x4 r0 = y0ok ? ld4u(ip - W) : zz;
        f32x4 r1 = ld4u(ip);
        f32x4 r2 = y2ok ? ld4u(ip + W) : zz;
        if (xlo) { r0[0] = 0.f; r1[0] = 0.f; r2[0] = 0.f; }
        if (ze2) { r0[2] = 0.f; r1[2] = 0.f; r2[2] = 0.f; }
        if (ze3) { r0[3] = 0.f; r1[3] = 0.f; r2[3] = 0.f; }
        const float* w0 = wb0 + cin * 9;
        const float* w1 = wb1 + cin * 9;
#pragma unroll
        for (int dy = 0; dy < 3; ++dy) {
            f32x4 r = (dy == 0) ? r0 : ((dy == 1) ? r1 : r2);
            float wa0 = w0[dy * 3], wa1 = w0[dy * 3 + 1], wa2 = w0[dy * 3 + 2];
            float wb0_ = w1[dy * 3], wb1_ = w1[dy * 3 + 1], wb2_ = w1[dy * 3 + 2];
            a00 = fmaf(r[0], wa0, a00); a00 = fmaf(r[1], wa1, a00); a00 = fmaf(r[2], wa2, a00);
            a01 = fmaf(r[1], wa0, a01); a01 = fmaf(r[2], wa1, a01); a01 = fmaf(r[3], wa2, a01);
            a10 = fmaf(r[0], wb0_, a10); a10 = fmaf(r[1], wb1_, a10); a10 = fmaf(r[2], wb2_, a10);
            a11 = fmaf(r[1], wb0_, a11); a11 = fmaf(r[2], wb1_, a11); a11 = fmaf(r[3], wb2_, a11);
        }
    }

    a00 = fmaxf(a00, 0.f); a01 = fmaxf(a01, 0.f);
    a10 = fmaxf(a10, 0.f); a11 = fmaxf(a11, 0.f);
    const int p0 = y * W + x0;
    if constexpr (OUTMODE == 0) {
        outf[((size_t)m * Cout + c0) * HW + p0] = a00;
        outf[((size_t)m * Cout + c0 + 1) * HW + p0] = a10;
        if (px1ok) {
            outf[((size_t)m * Cout + c0) * HW + p0 + 1] = a01;
            outf[((size_t)m * Cout + c0 + 1) * HW + p0 + 1] = a11;
        }
    } else {
        // bf16 [m][p][64]: 2 consecutive channels -> one dword store per px
        u32 v0 = (u32)f2bf(a00) | ((u32)f2bf(a10) << 16);
        *(u32*)(outb + ((size_t)m * HW + p0) * 64 + c0) = v0;
        if (px1ok) {
            u32 v1 = (u32)f2bf(a01) | ((u32)f2bf(a11) << 16);
            *(u32*)(outb + ((size_t)m * HW + p0 + 1) * 64 + c0) = v1;
        }
    }
}

// ---------------- final 64->1 conv + bias + residual, cin-split ----------------
// block: 64 px x 4 cin-splits(16 each); LDS reduce; grid (HW/64, M)
__global__ __launch_bounds__(256) void convlast_kernel(
    const float* __restrict__ in,   // [14][64][1024]
    const float* __restrict__ wts,  // [64][9]
    const float* __restrict__ bias, // [1]
    const float* __restrict__ resid,// [14][1024]
    float* __restrict__ out)        // [14][1024]
{
    __shared__ float red[256];
    const int t = threadIdx.x;
    const int pxl = t & 63;
    const int sp = t >> 6;
    const int px = blockIdx.x * 64 + pxl;
    const int m = blockIdx.y;
    const int y = px >> 5, x = px & 31;
    float a = 0.f;
    const float* im = in + ((size_t)m * 64 + sp * 16) * 1024 + y * 32 + x;
#pragma unroll 2
    for (int ci = 0; ci < 16; ++ci) {
        const float* ip = im + ci * 1024;
        const float* wr = wts + (sp * 16 + ci) * 9;
#pragma unroll
        for (int dy = 0; dy < 3; ++dy) {
            int yy = y + dy - 1;
            if (yy < 0 || yy >= 32) continue;
#pragma unroll
            for (int dx = 0; dx < 3; ++dx) {
                int xx = x + dx - 1;
                if (xx < 0 || xx >= 32) continue;
                a = fmaf(ip[(dy - 1) * 32 + (dx - 1)], wr[dy * 3 + dx], a);
            }
        }
    }
    red[t] = a;
    __syncthreads();
    if (t < 64) {
        int p = blockIdx.x * 64 + t;
        float vv = red[t] + red[t + 64] + red[t + 128] + red[t + 192]
                 + bias[0] + resid[(size_t)m * 1024 + p];
        out[(size_t)m * 1024 + p] = vv;
    }
}

// ---------------- fused MFMA MLP + softmax + epi + conf-combine ----------------
// grid 512 blocks (2 b x 256 n-groups of 4), block 256 thr = 4 waves.
// Rows r = (s*4 + nl)*32 + k: wave w has s = w>>1 (wave-uniform), 2 n values.
// L1 (normal): base = X@W1[1:65] + rank-1(flow,spat,b1) -> bf16 LDS (stride 72).
// L2 (transposed: A=W2^T regs, B=h1^T LDS) -> hidden in-lane; L3 = 2 shfl_xor.
// Softmax over k in-wave; conf-softmax over s in-block; writes novel directly.
__global__ __launch_bounds__(256, 2) void mlp_mfma_kernel(
    const float* __restrict__ lf, const float* __restrict__ flow,
    const u16* __restrict__ feat,   // [bs][2016][64] bf16
    const float* __restrict__ w1, const float* __restrict__ b1,
    const float* __restrict__ w2, const float* __restrict__ b2,
    const float* __restrict__ w3, const float* __restrict__ b3g,
    const float* __restrict__ cw, const float* __restrict__ cbg,
    float* __restrict__ novel)      // [b*7+v][1024]
{
    constexpr int SBS = 72; // s_base row stride (u16)
    __shared__ u16 s_w1[67 * 64];
    __shared__ u16 s_w2[64 * 64];
    __shared__ __align__(16) float s_vec[7 * 64]; // b1,b2,w3,cw,w1r0,w1r65,w1r66
    __shared__ __align__(16) float s_flow[256];
    __shared__ __align__(16) float s_epi[256];
    __shared__ __align__(16) u16 s_base[256 * SBS];
    __shared__ float s_nv[2][7][4];
    __shared__ float s_cf[2][7][4];

    const int t = threadIdx.x;
    const int blk = blockIdx.x;
    const int b = blk >> 8;
    const int n0 = (blk & 255) * 4;
    const int w = t >> 6, lane = t & 63, q = lane >> 4, l15 = lane & 15;
    const int sw = w >> 1;                 // wave's sparse-view index
    const int bsw = b * 2 + sw;

    for (int i = t; i < 67 * 64; i += 256) s_w1[i] = f2bf(w1[i]);
    for (int i = t; i < 64 * 64; i += 256) s_w2[i] = f2bf(w2[i]);
    if (t < 64) {
        s_vec[t]       = b1[t];
        s_vec[64 + t]  = b2[t];
        s_vec[128 + t] = w3[t];
        s_vec[192 + t] = cw[t];
        s_vec[256 + t] = w1[t];            // row 0: flow weight
        s_vec[320 + t] = w1[65 * 64 + t];  // row 65: spatial
        s_vec[384 + t] = w1[66 * 64 + t];  // row 66: ang
    }
    {
        int ss = t >> 7, nl = (t >> 5) & 3, k = t & 31;
        int n = n0 + nl;
        int a = ((b * 2 + ss) * 32 + (n >> 5)) * 63 + (n & 31) + k;
        s_flow[t] = flow[a];
        s_epi[t]  = lf[a];
    }
    __syncthreads();

    const float b3s = b3g[0];
    const float cbs = cbg[0];

    // ---- layer 1 ----
    FragU w1b[2][4];
#pragma unroll
    for (int ks = 0; ks < 2; ++ks)
#pragma unroll
        for (int nt = 0; nt < 4; ++nt)
#pragma unroll
            for (int jj = 0; jj < 8; ++jj)
                w1b[ks][nt].u[jj] = s_w1[(1 + ks * 32 + q * 8 + jj) * 64 + nt * 16 + l15];

    float w1r0pl[4], w1r65pl[4], b1pl[4];
#pragma unroll
    for (int nt = 0; nt < 4; ++nt) {
        int j1 = nt * 16 + l15;
        w1r0pl[nt]  = s_vec[256 + j1];
        w1r65pl[nt] = s_vec[320 + j1];
        b1pl[nt]    = s_vec[j1];
    }

#pragma unroll
    for (int mt = 0; mt < 4; ++mt) {
        const int rbase = w * 64 + mt * 16;
        FragU af[2];
        {
            int r = rbase + l15;
            int n = n0 + ((r >> 5) & 3);
            int pos = (n >> 5) * 63 + (n & 31) + (r & 31);
            const u16* fp = feat + ((size_t)bsw * 2016 + pos) * 64;
            af[0] = *(const FragU*)(fp + q * 8);
            af[1] = *(const FragU*)(fp + 32 + q * 8);
        }
        f32x4 flow4 = *(const f32x4*)(s_flow + rbase + q * 4);
#pragma unroll
        for (int nt = 0; nt < 4; ++nt) {
            f32x4 d = {0.f, 0.f, 0.f, 0.f};
            d = __builtin_amdgcn_mfma_f32_16x16x32_bf16(af[0].v, w1b[0][nt].v, d, 0, 0, 0);
            d = __builtin_amdgcn_mfma_f32_16x16x32_bf16(af[1].v, w1b[1][nt].v, d, 0, 0, 0);
#pragma unroll
            for (int e = 0; e < 4; ++e) {
                int r = rbase + q * 4 + e;
                int k = r & 31;
                float val = d[e] + flow4[e] * w1r0pl[nt]
                          + (float)(k - 16) * w1r65pl[nt] + b1pl[nt];
                s_base[r * SBS + nt * 16 + l15] = f2bf(val);
            }
        }
    }
    __syncthreads();

    // ---- preloads for v-loop ----
    FragU w2a[4][2]; // A = W2^T
#pragma unroll
    for (int mt = 0; mt < 4; ++mt)
#pragma unroll
        for (int ks = 0; ks < 2; ++ks)
#pragma unroll
            for (int jj = 0; jj < 8; ++jj)
                w2a[mt][ks].u[jj] = s_w2[(ks * 32 + q * 8 + jj) * 64 + mt * 16 + l15];

    float w66pl[2][8];
#pragma unroll
    for (int ks = 0; ks < 2; ++ks)
#pragma unroll
        for (int jj = 0; jj < 8; ++jj)
            w66pl[ks][jj] = s_vec[384 + ks * 32 + q * 8 + jj];

    float b2pl[4][4], w3pl[4][4], cwpl[4][4];
#pragma unroll
    for (int mt = 0; mt < 4; ++mt)
#pragma unroll
        for (int e = 0; e < 4; ++e) {
            b2pl[mt][e] = s_vec[64 + mt * 16 + q * 4 + e];
            w3pl[mt][e] = s_vec[128 + mt * 16 + q * 4 + e];
            cwpl[mt][e] = s_vec[192 + mt * 16 + q * 4 + e];
        }
    float epi_pl[4];
#pragma unroll
    for (int nt = 0; nt < 4; ++nt) epi_pl[nt] = s_epi[w * 64 + nt * 16 + l15];

    // ---- per-view loop ----
    for (int v = 0; v < 7; ++v) {
        float ang = (sw == 0) ? -(float)(v + 1) : (float)(7 - v);
        f32x4 acc[4][4];
#pragma unroll
        for (int nt = 0; nt < 4; ++nt) {
            FragU bfr[2]; // B = h1^T
#pragma unroll
            for (int ks = 0; ks < 2; ++ks) {
                const u16x8 raw = *(const u16x8*)(s_base + (w * 64 + nt * 16 + l15) * SBS + ks * 32 + q * 8);
#pragma unroll
                for (int jj = 0; jj < 8; ++jj) {
                    float xv = bf2f(raw[jj]);
                    float hv = fmaxf(xv + ang * w66pl[ks][jj], 0.f);
                    bfr[ks].u[jj] = f2bf(hv);
                }
            }
#pragma unroll
            for (int mt = 0; mt < 4; ++mt) {
                f32x4 d = {0.f, 0.f, 0.f, 0.f};
                d = __builtin_amdgcn_mfma_f32_16x16x32_bf16(w2a[mt][0].v, bfr[0].v, d, 0, 0, 0);
                d = __builtin_amdgcn_mfma_f32_16x16x32_bf16(w2a[mt][1].v, bfr[1].v, d, 0, 0, 0);
                acc[mt][nt] = d;
            }
        }
        float wl[4], cfl[4];
#pragma unroll
        for (int nt = 0; nt < 4; ++nt) {
            float wls = 0.f, cfs = 0.f;
#pragma unroll
            for (int mt = 0; mt < 4; ++mt)
#pragma unroll
                for (int e = 0; e < 4; ++e) {
                    float h2 = fmaxf(acc[mt][nt][e] + b2pl[mt][e], 0.f);
                    wls += h2 * w3pl[mt][e];
                    cfs += h2 * cwpl[mt][e];
                }
            wls += __shfl_xor(wls, 16); wls += __shfl_xor(wls, 32);
            cfs += __shfl_xor(cfs, 16); cfs += __shfl_xor(cfs, 32);
            wl[nt]  = wls + b3s;
            cfl[nt] = cfs;
        }
#pragma unroll
        for (int ni = 0; ni < 2; ++ni) {
            float a0 = wl[ni * 2], a1 = wl[ni * 2 + 1];
            float mx = fmaxf(a0, a1);
#pragma unroll
            for (int msk = 1; msk <= 8; msk <<= 1) mx = fmaxf(mx, __shfl_xor(mx, msk));
            float e0 = __expf(a0 - mx), e1 = __expf(a1 - mx);
            float ssum = e0 + e1;
            float nvp = e0 * epi_pl[ni * 2] + e1 * epi_pl[ni * 2 + 1];
            float cfp = cfl[ni * 2] + cfl[ni * 2 + 1];
#pragma unroll
            for (int msk = 1; msk <= 8; msk <<= 1) {
                ssum += __shfl_xor(ssum, msk);
                nvp  += __shfl_xor(nvp, msk);
                cfp  += __shfl_xor(cfp, msk);
            }
            if (lane == 0) {
                int nloc = (w & 1) * 2 + ni;
                s_nv[sw][v][nloc] = nvp / ssum;
                s_cf[sw][v][nloc] = cfp * (1.f / 32.f) + cbs;
            }
        }
    }
    __syncthreads();

    // ---- conf softmax over s + write novel ----
    if (t < 28) {
        int v = t >> 2, nl = t & 3;
        float c0 = s_cf[0][v][nl], c1 = s_cf[1][v][nl];
        float mx = fmaxf(c0, c1);
        float e0 = __expf(c0 - mx), e1 = __expf(c1 - mx);
        novel[(size_t)(b * 7 + v) * 1024 + n0 + nl] =
            (e0 * s_nv[0][v][nl] + e1 * s_nv[1][v][nl]) / (e0 + e1);
    }
}

// ---------------- launch ----------------
extern "C" void kernel_launch(void* const* d_in, const int* in_sizes, int n_in,
                              void* d_out, int out_size, void* d_ws, size_t ws_size,
                              hipStream_t stream) {
    const float* lf   = (const float*)d_in[0];
    const float* flow = (const float*)d_in[1];
    const float* wp   = (const float*)d_in[2];
    const float* pl   = (const float*)d_in[3];
    const float* pr   = (const float*)d_in[4];
    const float* frw1 = (const float*)d_in[5];
    const float* frb1 = (const float*)d_in[6];
    const float* frw2 = (const float*)d_in[7];
    const float* frb2 = (const float*)d_in[8];
    const float* frw3 = (const float*)d_in[9];
    const float* frb3 = (const float*)d_in[10];
    const float* mw1  = (const float*)d_in[11];
    const float* mb1  = (const float*)d_in[12];
    const float* mw2  = (const float*)d_in[13];
    const float* mb2  = (const float*)d_in[14];
    const float* mw3  = (const float*)d_in[15];
    const float* mb3  = (const float*)d_in[16];
    const float* cwp  = (const float*)d_in[17];
    const float* cbp  = (const float*)d_in[18];
    const float* vrw1 = (const float*)d_in[19];
    const float* vrb1 = (const float*)d_in[20];
    const float* vrw2 = (const float*)d_in[21];
    const float* vrb2 = (const float*)d_in[22];
    const float* vrw3 = (const float*)d_in[23];
    const float* vrb3 = (const float*)d_in[24];
    float* ws = (float*)d_ws;

    // feature net on (4,*,32,63); concat order [flow, lf, wp]
    conv3_kernel<8><<<dim3(8, 8, 4), 256, 0, stream>>>(
        flow, lf, wp, frw1, frb1, ws + FEAT_A, 32, 63, 64);
    conv64_kernel<0><<<dim3(32, 4, 4), 256, 0, stream>>>(
        ws + FEAT_A, frw2, frb2, ws + FEAT_B, nullptr, 32, 63, 32, 64);
    conv64_kernel<1><<<dim3(32, 4, 4), 256, 0, stream>>>(
        ws + FEAT_B, frw3, frb3, nullptr, (u16*)(ws + FEATBF), 32, 63, 32, 64);

    // MLP + softmax + epi + conf-combine -> novel
    mlp_mfma_kernel<<<512, 256, 0, stream>>>(
        lf, flow, (const u16*)(ws + FEATBF),
        mw1, mb1, mw2, mb2, mw3, mb3, cwp, cbp,
        ws + NOVEL);

    // refinement net on (14,*,32,32); concat order [pn, pl, pr]
    conv3_kernel<8><<<dim3(8, 4, 14), 256, 0, stream>>>(
        ws + NOVEL, pl, pr, vrw1, vrb1, ws + FEAT_A, 32, 32, 64);
    conv64_kernel<0><<<dim3(32, 2, 14), 256, 0, stream>>>(
        ws + FEAT_A, vrw2, vrb2, ws + FEAT_B, nullptr, 32, 32, 16, 64);
    convlast_kernel<<<dim3(16, 14), 256, 0, stream>>>(
        ws + FEAT_B, vrw3, vrb3, ws + NOVEL, (float*)d_out);
}